// Round 2
// baseline (2994.679 us; speedup 1.0000x reference)
//
#include <hip/hip_runtime.h>
#include <stdint.h>

#define HID 512
#define BAT 256

typedef __attribute__((ext_vector_type(8)))  short short8;
typedef __attribute__((ext_vector_type(16))) float floatx16;

static __device__ __forceinline__ unsigned short f2bf(float f) {
  union { float f; uint32_t u; } v; v.f = f;
  uint32_t u = v.u + (((v.u >> 16) & 1u) + 0x7FFFu);   // round-to-nearest-even
  return (unsigned short)(u >> 16);
}
static __device__ __forceinline__ float bf2f(unsigned short h) {
  union { uint32_t u; float f; } v; v.u = ((uint32_t)h) << 16;
  return v.f;
}
static __device__ __forceinline__ float fast_tanh(float v) {
  float e = __expf(2.0f * v);
  return 1.0f - 2.0f / (e + 1.0f);
}

// K0: split Wl AND Wr into hi/lo bf16 fragments in MFMA B-fragment order per
// 32-col block: frag[(j*32+kc)*64 + lane][jj], n = j*32+(l&31), k = kc*16+(l>>5)*8+jj.
// Also zero the 128 sync flags (ws is re-poisoned before every timed launch).
extern "C" __global__ __launch_bounds__(64) void rk0_frag(
    const float* __restrict__ Wl, const float* __restrict__ Wr,
    unsigned short* __restrict__ wlhi, unsigned short* __restrict__ wllo,
    unsigned short* __restrict__ wrhi, unsigned short* __restrict__ wrlo,
    int* __restrict__ flags) {
  int blk = blockIdx.x, l = threadIdx.x;
  if (l == 0 && blk < 128) flags[blk * 32] = 0;
  int j = blk >> 5, kc = blk & 31;
  int n = j * 32 + (l & 31);
  int kb = kc * 16 + ((l >> 5) << 3);
  size_t ob = ((size_t)blk * 64 + l) * 8;
#pragma unroll
  for (int jj = 0; jj < 8; ++jj) {
    int k = kb + jj;
    float wl = Wl[(size_t)k * HID + n];
    unsigned short hi = f2bf(wl);
    wlhi[ob + jj] = hi;
    wllo[ob + jj] = f2bf(wl - bf2f(hi));
    float wr = Wr[(size_t)k * HID + n];
    unsigned short hi2 = f2bf(wr);
    wrhi[ob + jj] = hi2;
    wrlo[ob + jj] = f2bf(wr - bf2f(hi2));
  }
}

// K1: Rf[kb] = emb[tok(kb)] @ (kb==0 ? Wl : Wr) (+ bias for kb>0), computed in
// ~f32 precision via hi/lo split of BOTH operands (3 MFMAs), stored as f32 in
// the C-fragment order K2 consumes: Rf[kb*131072 + (i*16+j)*1024 + l*16 + r]
extern "C" __global__ __launch_bounds__(256, 1) void rk1_pre(
    const int* __restrict__ tokens, const float* __restrict__ emb,
    const float* __restrict__ bias,
    const unsigned short* __restrict__ wlhi, const unsigned short* __restrict__ wllo,
    const unsigned short* __restrict__ wrhi, const unsigned short* __restrict__ wrlo,
    float* __restrict__ Rf) {
  __shared__ uint4 ldsh[2048];  // 32KB: Wr hi frags for col-block j
  __shared__ uint4 ldsl[2048];  // 32KB: Wr lo frags
  int j = blockIdx.x, i = blockIdx.y, z = blockIdx.z;
  int tid = threadIdx.x;
  {
    const uint4* sh = (const uint4*)wrhi + (size_t)j * 2048;
    const uint4* sl = (const uint4*)wrlo + (size_t)j * 2048;
#pragma unroll
    for (int it = 0; it < 8; ++it) {
      ldsh[it * 256 + tid] = sh[it * 256 + tid];
      ldsl[it * 256 + tid] = sl[it * 256 + tid];
    }
  }
  __syncthreads();
  int w = tid >> 6, l = tid & 63;
  int kb = z * 4 + w;                       // 0..255
  int b = i * 32 + (l & 31);
  int t = (kb == 0) ? 0 : (2 * kb - 1);
  int tok = tokens[t * BAT + b];
  const float* ar = emb + (size_t)tok * HID + ((l >> 5) << 3);
  const uint4* bh0 = (const uint4*)wlhi + (size_t)j * 2048;  // kb==0 uses Wl
  const uint4* bl0 = (const uint4*)wllo + (size_t)j * 2048;
  floatx16 acc = {};
#pragma unroll 4
  for (int kc = 0; kc < 32; ++kc) {
    float4 a0 = *(const float4*)(ar + kc * 16);
    float4 a1 = *(const float4*)(ar + kc * 16 + 4);
    float av[8] = {a0.x, a0.y, a0.z, a0.w, a1.x, a1.y, a1.z, a1.w};
    unsigned short ah[8], alo[8];
#pragma unroll
    for (int m = 0; m < 8; ++m) {
      unsigned short hi = f2bf(av[m]);
      ah[m] = hi;
      alo[m] = f2bf(av[m] - bf2f(hi));
    }
    uint4 ahi4, alo4;
    ahi4.x = ah[0] | ((uint32_t)ah[1] << 16);  ahi4.y = ah[2] | ((uint32_t)ah[3] << 16);
    ahi4.z = ah[4] | ((uint32_t)ah[5] << 16);  ahi4.w = ah[6] | ((uint32_t)ah[7] << 16);
    alo4.x = alo[0] | ((uint32_t)alo[1] << 16); alo4.y = alo[2] | ((uint32_t)alo[3] << 16);
    alo4.z = alo[4] | ((uint32_t)alo[5] << 16); alo4.w = alo[6] | ((uint32_t)alo[7] << 16);
    uint4 bh = (kb == 0) ? bh0[kc * 64 + l] : ldsh[kc * 64 + l];
    uint4 bl = (kb == 0) ? bl0[kc * 64 + l] : ldsl[kc * 64 + l];
    short8 avh = __builtin_bit_cast(short8, ahi4);
    short8 avl = __builtin_bit_cast(short8, alo4);
    short8 bvh = __builtin_bit_cast(short8, bh);
    short8 bvl = __builtin_bit_cast(short8, bl);
    acc = __builtin_amdgcn_mfma_f32_32x32x16_bf16(avh, bvh, acc, 0, 0, 0);
    acc = __builtin_amdgcn_mfma_f32_32x32x16_bf16(avh, bvl, acc, 0, 0, 0);
    acc = __builtin_amdgcn_mfma_f32_32x32x16_bf16(avl, bvh, acc, 0, 0, 0);
  }
  int col = j * 32 + (l & 31);
  float bvv = (kb == 0) ? 0.0f : bias[col];
  float* dst = Rf + ((size_t)kb * 131072 + ((size_t)i * 16 + j) * 1024 + (size_t)l * 16);
  float4 o0 = {acc[0] + bvv, acc[1] + bvv, acc[2] + bvv, acc[3] + bvv};
  float4 o1 = {acc[4] + bvv, acc[5] + bvv, acc[6] + bvv, acc[7] + bvv};
  float4 o2 = {acc[8] + bvv, acc[9] + bvv, acc[10] + bvv, acc[11] + bvv};
  float4 o3 = {acc[12] + bvv, acc[13] + bvv, acc[14] + bvv, acc[15] + bvv};
  ((float4*)dst)[0] = o0; ((float4*)dst)[1] = o1;
  ((float4*)dst)[2] = o2; ((float4*)dst)[3] = o3;
}

// K2: persistent recurrence. 128 WGs = 8 row-blocks (i) x 16 col-blocks (j),
// 1 wave each. Wl hi/lo frags resident in LDS. h exchanged via global hi/lo
// bf16 planes, double-buffered, flag-synced per step. R read as f32.
extern "C" __global__ __launch_bounds__(64, 1) void rk2_rec(
    const unsigned short* __restrict__ wlhi, const unsigned short* __restrict__ wllo,
    const float* __restrict__ Rf,
    unsigned short* hhi, unsigned short* hlo, int* flags,
    float* __restrict__ out) {
  __shared__ uint4 lds[4096];  // 64KB: [0,2048) Wl-hi frags, [2048,4096) Wl-lo
  int idx = blockIdx.x;
  int i = idx & 7, j = idx >> 3;  // idx%8==i -> row-group shares an XCD (locality hint)
  int l = threadIdx.x;
  {
    const uint4* sh = (const uint4*)wlhi + (size_t)j * 2048;
    const uint4* sl = (const uint4*)wllo + (size_t)j * 2048;
#pragma unroll 4
    for (int it = 0; it < 32; ++it) {
      lds[it * 64 + l] = sh[it * 64 + l];
      lds[2048 + it * 64 + l] = sl[it * 64 + l];
    }
  }
  __syncthreads();
  int col = j * 32 + (l & 31);
  int r4 = (l >> 5) << 2;
  int arow = i * 32 + (l & 31);
  int koff = (l >> 5) << 3;
  size_t fragbase = ((size_t)i * 16 + j) * 1024 + (size_t)l * 16;  // in floats
  int fi = (i * 16 + j) * 32;
  float x[16];

  // ---- step 1: h1 = tanh(R0 + R1) (both precomputed f32, C-frag layout) ----
  {
    const float4* r0 = (const float4*)(Rf + fragbase);
    const float4* r1 = (const float4*)(Rf + (size_t)131072 + fragbase);
#pragma unroll
    for (int q = 0; q < 4; ++q) {
      float4 a = r0[q], b = r1[q];
      x[q * 4 + 0] = fast_tanh(a.x + b.x);
      x[q * 4 + 1] = fast_tanh(a.y + b.y);
      x[q * 4 + 2] = fast_tanh(a.z + b.z);
      x[q * 4 + 3] = fast_tanh(a.w + b.w);
    }
  }
#pragma unroll
  for (int r = 0; r < 16; ++r) {  // store h1 into parity-1 buffer
    int row = i * 32 + r4 + (r & 3) + ((r >> 2) << 3);
    unsigned short h = f2bf(x[r]);
    hhi[(size_t)(BAT * HID) + (size_t)row * HID + col] = h;
    hlo[(size_t)(BAT * HID) + (size_t)row * HID + col] = f2bf(x[r] - bf2f(h));
  }
  __threadfence();
  if (l == 0) __hip_atomic_store(&flags[fi], 1, __ATOMIC_RELAXED, __HIP_MEMORY_SCOPE_AGENT);

  // ---- steps 2..255 ----
  for (int s = 2; s <= 255; ++s) {
    float rv[16];
    {  // prefetch R_s (no dependency on the flag)
      const float4* rp = (const float4*)(Rf + (size_t)s * 131072 + fragbase);
#pragma unroll
      for (int q = 0; q < 4; ++q) {
        float4 a = rp[q];
        rv[q * 4 + 0] = a.x; rv[q * 4 + 1] = a.y;
        rv[q * 4 + 2] = a.z; rv[q * 4 + 3] = a.w;
      }
    }
    if (l < 16) {
      while (__hip_atomic_load(&flags[(i * 16 + l) * 32], __ATOMIC_RELAXED,
                               __HIP_MEMORY_SCOPE_AGENT) < s - 1) {}
    }
    __threadfence();  // acquire: invalidate stale caches before reading h
    size_t hb = (size_t)((s - 1) & 1) * (BAT * HID) + (size_t)arow * HID + koff;
    const unsigned short* Ah = hhi + hb;
    const unsigned short* Al = hlo + hb;
    floatx16 acc0 = {}, acc1 = {}, acc2 = {};
#pragma unroll 4
    for (int kc = 0; kc < 32; ++kc) {
      short8 ah = *(const short8*)(Ah + kc * 16);
      short8 al = *(const short8*)(Al + kc * 16);
      short8 bh = __builtin_bit_cast(short8, lds[kc * 64 + l]);
      short8 bl = __builtin_bit_cast(short8, lds[2048 + kc * 64 + l]);
      acc0 = __builtin_amdgcn_mfma_f32_32x32x16_bf16(ah, bh, acc0, 0, 0, 0);
      acc1 = __builtin_amdgcn_mfma_f32_32x32x16_bf16(ah, bl, acc1, 0, 0, 0);
      acc2 = __builtin_amdgcn_mfma_f32_32x32x16_bf16(al, bh, acc2, 0, 0, 0);
    }
#pragma unroll
    for (int r = 0; r < 16; ++r)
      x[r] = fast_tanh(acc0[r] + acc1[r] + acc2[r] + rv[r]);
    if (s < 255) {
      size_t base = (size_t)(s & 1) * (BAT * HID);
#pragma unroll
      for (int r = 0; r < 16; ++r) {
        int row = i * 32 + r4 + (r & 3) + ((r >> 2) << 3);
        unsigned short h = f2bf(x[r]);
        hhi[base + (size_t)row * HID + col] = h;
        hlo[base + (size_t)row * HID + col] = f2bf(x[r] - bf2f(h));
      }
      __threadfence();  // release: flush before publishing the flag
      if (l == 0) __hip_atomic_store(&flags[fi], s, __ATOMIC_RELAXED, __HIP_MEMORY_SCOPE_AGENT);
    } else {
#pragma unroll
      for (int r = 0; r < 16; ++r) {
        int row = i * 32 + r4 + (r & 3) + ((r >> 2) << 3);
        out[(size_t)row * HID + col] = x[r];
      }
    }
  }
}

extern "C" void kernel_launch(void* const* d_in, const int* in_sizes, int n_in,
                              void* d_out, int out_size, void* d_ws, size_t ws_size,
                              hipStream_t stream) {
  const int*   tokens = (const int*)d_in[0];
  const float* emb    = (const float*)d_in[1];
  const float* Wl     = (const float*)d_in[2];
  const float* Wr     = (const float*)d_in[3];
  const float* bias   = (const float*)d_in[4];
  float* out = (float*)d_out;
  char* ws = (char*)d_ws;
  const size_t HALF_MB = 1u << 19;
  unsigned short* wlhi = (unsigned short*)(ws + 0 * HALF_MB);  // 0.5MB each
  unsigned short* wllo = (unsigned short*)(ws + 1 * HALF_MB);
  unsigned short* wrhi = (unsigned short*)(ws + 2 * HALF_MB);
  unsigned short* wrlo = (unsigned short*)(ws + 3 * HALF_MB);
  unsigned short* hhi  = (unsigned short*)(ws + 4 * HALF_MB);  // 2 x 256x512 bf16
  unsigned short* hlo  = (unsigned short*)(ws + 5 * HALF_MB);
  int* flags           = (int*)(ws + 6 * HALF_MB);             // 16KB
  float* Rf            = (float*)(ws + 8 * HALF_MB);           // 134MB f32

  hipLaunchKernelGGL(rk0_frag, dim3(512), dim3(64), 0, stream,
                     Wl, Wr, wlhi, wllo, wrhi, wrlo, flags);
  hipLaunchKernelGGL(rk1_pre, dim3(16, 8, 64), dim3(256), 0, stream,
                     tokens, emb, bias, wlhi, wllo, wrhi, wrlo, Rf);
  hipLaunchKernelGGL(rk2_rec, dim3(128), dim3(64), 0, stream,
                     wlhi, wllo, Rf, hhi, hlo, flags, out);
}

// Round 3
// 2188.083 us; speedup vs baseline: 1.3686x; 1.3686x over previous
//
#include <hip/hip_runtime.h>
#include <stdint.h>

#define HID 512
#define BAT 256

typedef __attribute__((ext_vector_type(8)))  short short8;
typedef __attribute__((ext_vector_type(16))) float floatx16;

static __device__ __forceinline__ unsigned short f2bf(float f) {
  union { float f; uint32_t u; } v; v.f = f;
  uint32_t u = v.u + (((v.u >> 16) & 1u) + 0x7FFFu);   // round-to-nearest-even
  return (unsigned short)(u >> 16);
}
static __device__ __forceinline__ float bf2f(unsigned short h) {
  union { uint32_t u; float f; } v; v.u = ((uint32_t)h) << 16;
  return v.f;
}
static __device__ __forceinline__ float fast_tanh(float v) {
  float e = __expf(2.0f * v);
  return 1.0f - 2.0f / (e + 1.0f);
}

// K0: split Wl into hi/lo bf16 fragments, Wr into hi fragments, MFMA B-frag
// order per 32-col block: frag[(j*32+kc)*64 + lane][jj]; n = j*32+(l&31),
// k = kc*16+(l>>5)*8+jj. Also zero the 128 sync flags.
extern "C" __global__ __launch_bounds__(64) void rk0_frag(
    const float* __restrict__ Wl, const float* __restrict__ Wr,
    unsigned short* __restrict__ wlhi, unsigned short* __restrict__ wllo,
    unsigned short* __restrict__ wrhi, int* __restrict__ flags) {
  int blk = blockIdx.x, l = threadIdx.x;
  if (l == 0 && blk < 128) flags[blk * 32] = 0;
  int j = blk >> 5, kc = blk & 31;
  int n = j * 32 + (l & 31);
  int kb = kc * 16 + ((l >> 5) << 3);
  size_t ob = ((size_t)blk * 64 + l) * 8;
#pragma unroll
  for (int jj = 0; jj < 8; ++jj) {
    int k = kb + jj;
    float wl = Wl[(size_t)k * HID + n];
    unsigned short hi = f2bf(wl);
    wlhi[ob + jj] = hi;
    wllo[ob + jj] = f2bf(wl - bf2f(hi));
    wrhi[ob + jj] = f2bf(Wr[(size_t)k * HID + n]);
  }
}

// K1: Rf[kb] = emb[tok(kb)] @ (kb==0 ? Wl : Wr) (+ bias for kb>0), emb-hi x
// W-hi single MFMA, f32 storage (the precision-critical part is f32 storage).
// One WG per (i, z): emb A-frags gathered ONCE into regs, then looped over all
// 16 col-blocks -> kills the 16x emb re-fetch of the previous version.
extern "C" __global__ __launch_bounds__(256, 1) void rk1_pre(
    const int* __restrict__ tokens, const float* __restrict__ emb,
    const float* __restrict__ bias,
    const unsigned short* __restrict__ wlhi, const unsigned short* __restrict__ wrhi,
    float* __restrict__ Rf) {
  __shared__ uint4 ldsb[2048];  // 32KB: Wr-hi frags for current col-block j
  int i = blockIdx.x, z = blockIdx.y;
  int tid = threadIdx.x, w = tid >> 6, l = tid & 63;
  int kb = z * 4 + w;                      // 0..255
  int b = i * 32 + (l & 31);
  int t = (kb == 0) ? 0 : (2 * kb - 1);
  int tok = tokens[t * BAT + b];
  int koff = (l >> 5) << 3;
  const float* ar = emb + (size_t)tok * HID + koff;
  uint32_t af[32][4];                      // A-frags (hi) in 128 VGPRs
#pragma unroll
  for (int kc = 0; kc < 32; ++kc) {
    float4 a0 = *(const float4*)(ar + kc * 16);
    float4 a1 = *(const float4*)(ar + kc * 16 + 4);
    af[kc][0] = (uint32_t)f2bf(a0.x) | ((uint32_t)f2bf(a0.y) << 16);
    af[kc][1] = (uint32_t)f2bf(a0.z) | ((uint32_t)f2bf(a0.w) << 16);
    af[kc][2] = (uint32_t)f2bf(a1.x) | ((uint32_t)f2bf(a1.y) << 16);
    af[kc][3] = (uint32_t)f2bf(a1.z) | ((uint32_t)f2bf(a1.w) << 16);
  }
  for (int jb = 0; jb < 16; ++jb) {
    __syncthreads();   // protect previous iteration's LDS reads
    {
      const uint4* src = (const uint4*)wrhi + (size_t)jb * 2048;
#pragma unroll
      for (int it = 0; it < 8; ++it) ldsb[it * 256 + tid] = src[it * 256 + tid];
    }
    __syncthreads();
    floatx16 acc = {};
    if (kb == 0) {     // wave-uniform: the one kb==0 wave uses Wl straight from global
      const uint4* bglob = (const uint4*)wlhi + (size_t)jb * 2048;
#pragma unroll 8
      for (int kc = 0; kc < 32; ++kc) {
        uint4 a4; a4.x = af[kc][0]; a4.y = af[kc][1]; a4.z = af[kc][2]; a4.w = af[kc][3];
        uint4 b4 = bglob[kc * 64 + l];
        acc = __builtin_amdgcn_mfma_f32_32x32x16_bf16(
            __builtin_bit_cast(short8, a4), __builtin_bit_cast(short8, b4), acc, 0, 0, 0);
      }
    } else {
#pragma unroll 8
      for (int kc = 0; kc < 32; ++kc) {
        uint4 a4; a4.x = af[kc][0]; a4.y = af[kc][1]; a4.z = af[kc][2]; a4.w = af[kc][3];
        uint4 b4 = ldsb[kc * 64 + l];
        acc = __builtin_amdgcn_mfma_f32_32x32x16_bf16(
            __builtin_bit_cast(short8, a4), __builtin_bit_cast(short8, b4), acc, 0, 0, 0);
      }
    }
    int col = jb * 32 + (l & 31);
    float bvv = (kb == 0) ? 0.0f : bias[col];
    float* dst = Rf + (size_t)kb * 131072 + ((size_t)i * 16 + jb) * 1024 + (size_t)l * 16;
    float4 o0 = {acc[0] + bvv,  acc[1] + bvv,  acc[2] + bvv,  acc[3] + bvv};
    float4 o1 = {acc[4] + bvv,  acc[5] + bvv,  acc[6] + bvv,  acc[7] + bvv};
    float4 o2 = {acc[8] + bvv,  acc[9] + bvv,  acc[10] + bvv, acc[11] + bvv};
    float4 o3 = {acc[12] + bvv, acc[13] + bvv, acc[14] + bvv, acc[15] + bvv};
    ((float4*)dst)[0] = o0; ((float4*)dst)[1] = o1;
    ((float4*)dst)[2] = o2; ((float4*)dst)[3] = o3;
  }
}

// K2: persistent recurrence, fence-free protocol. h exchanged as packed
// uint32 (hi|lo bf16) via SYSTEM-scope relaxed atomics (sc0|sc1 write-through /
// cache-bypass). Flags published after s_waitcnt vmcnt(0). Per-step reads are
// pipelined in 4 groups of 8 k-chunks with double-buffered register staging.
#define WAITG(g)                                                                   \
  do {                                                                             \
    if (l < 4) {                                                                   \
      int p_ = (g)*4 + l;                                                          \
      if (p_ != j) {                                                               \
        while (__hip_atomic_load(&flags[(fbase + p_) * 32], __ATOMIC_RELAXED,      \
                                 __HIP_MEMORY_SCOPE_SYSTEM) < s - 1) {}            \
      }                                                                            \
    }                                                                              \
  } while (0)

#define LOADG(g, A_)                                                               \
  do {                                                                             \
    _Pragma("unroll") for (int c_ = 0; c_ < 8; ++c_) {                             \
      const unsigned long long* p8_ =                                              \
          (const unsigned long long*)(hb + abase + ((g)*8 + c_) * 16);             \
      A_[c_ * 4 + 0] = __hip_atomic_load(p8_ + 0, __ATOMIC_RELAXED,                \
                                         __HIP_MEMORY_SCOPE_SYSTEM);               \
      A_[c_ * 4 + 1] = __hip_atomic_load(p8_ + 1, __ATOMIC_RELAXED,                \
                                         __HIP_MEMORY_SCOPE_SYSTEM);               \
      A_[c_ * 4 + 2] = __hip_atomic_load(p8_ + 2, __ATOMIC_RELAXED,                \
                                         __HIP_MEMORY_SCOPE_SYSTEM);               \
      A_[c_ * 4 + 3] = __hip_atomic_load(p8_ + 3, __ATOMIC_RELAXED,                \
                                         __HIP_MEMORY_SCOPE_SYSTEM);               \
    }                                                                              \
  } while (0)

#define CONSUME(g, A_)                                                             \
  do {                                                                             \
    _Pragma("unroll") for (int c_ = 0; c_ < 8; ++c_) {                             \
      int kc_ = (g)*8 + c_;                                                        \
      uint32_t w0 = (uint32_t)A_[c_ * 4 + 0], w1 = (uint32_t)(A_[c_ * 4 + 0] >> 32); \
      uint32_t w2 = (uint32_t)A_[c_ * 4 + 1], w3 = (uint32_t)(A_[c_ * 4 + 1] >> 32); \
      uint32_t w4 = (uint32_t)A_[c_ * 4 + 2], w5 = (uint32_t)(A_[c_ * 4 + 2] >> 32); \
      uint32_t w6 = (uint32_t)A_[c_ * 4 + 3], w7 = (uint32_t)(A_[c_ * 4 + 3] >> 32); \
      uint4 ahw, alw;                                                              \
      ahw.x = __builtin_amdgcn_perm(w1, w0, 0x05040100u);                          \
      alw.x = __builtin_amdgcn_perm(w1, w0, 0x07060302u);                          \
      ahw.y = __builtin_amdgcn_perm(w3, w2, 0x05040100u);                          \
      alw.y = __builtin_amdgcn_perm(w3, w2, 0x07060302u);                          \
      ahw.z = __builtin_amdgcn_perm(w5, w4, 0x05040100u);                          \
      alw.z = __builtin_amdgcn_perm(w5, w4, 0x07060302u);                          \
      ahw.w = __builtin_amdgcn_perm(w7, w6, 0x05040100u);                          \
      alw.w = __builtin_amdgcn_perm(w7, w6, 0x07060302u);                          \
      short8 ah = __builtin_bit_cast(short8, ahw);                                 \
      short8 al = __builtin_bit_cast(short8, alw);                                 \
      short8 bh = __builtin_bit_cast(short8, lds[kc_ * 64 + l]);                   \
      short8 bl = __builtin_bit_cast(short8, lds[2048 + kc_ * 64 + l]);            \
      acc0 = __builtin_amdgcn_mfma_f32_32x32x16_bf16(ah, bh, acc0, 0, 0, 0);       \
      acc1 = __builtin_amdgcn_mfma_f32_32x32x16_bf16(ah, bl, acc1, 0, 0, 0);       \
      acc2 = __builtin_amdgcn_mfma_f32_32x32x16_bf16(al, bh, acc2, 0, 0, 0);       \
    }                                                                              \
  } while (0)

extern "C" __global__ __launch_bounds__(64, 1) void rk2_rec(
    const unsigned short* __restrict__ wlhi, const unsigned short* __restrict__ wllo,
    const float* __restrict__ Rf,
    uint32_t* hpk, int* flags, float* __restrict__ out) {
  __shared__ uint4 lds[4096];  // 64KB: [0,2048) Wl-hi frags, [2048,4096) Wl-lo
  int idx = blockIdx.x;
  int i = idx & 7, j = idx >> 3;  // idx%8==i -> row-group spread across XCDs
  int l = threadIdx.x;
  {
    const uint4* sh = (const uint4*)wlhi + (size_t)j * 2048;
    const uint4* sl = (const uint4*)wllo + (size_t)j * 2048;
#pragma unroll 4
    for (int it = 0; it < 32; ++it) {
      lds[it * 64 + l] = sh[it * 64 + l];
      lds[2048 + it * 64 + l] = sl[it * 64 + l];
    }
  }
  __syncthreads();
  int col = j * 32 + (l & 31);
  int r4 = (l >> 5) << 2;
  int arow = i * 32 + (l & 31);
  int koff = (l >> 5) << 3;
  size_t fragbase = ((size_t)i * 16 + j) * 1024 + (size_t)l * 16;  // floats
  int fbase = i * 16;
  int myflag = (i * 16 + j) * 32;
  size_t abase = (size_t)arow * HID + koff;  // uint32 elements within a parity plane
  float x[16];

  // ---- step 1: h1 = tanh(R0 + R1) ----
  {
    const float4* r0 = (const float4*)(Rf + fragbase);
    const float4* r1 = (const float4*)(Rf + (size_t)131072 + fragbase);
#pragma unroll
    for (int q = 0; q < 4; ++q) {
      float4 a = r0[q], b = r1[q];
      x[q * 4 + 0] = fast_tanh(a.x + b.x);
      x[q * 4 + 1] = fast_tanh(a.y + b.y);
      x[q * 4 + 2] = fast_tanh(a.z + b.z);
      x[q * 4 + 3] = fast_tanh(a.w + b.w);
    }
  }
  {
    uint32_t* dstp = hpk + (size_t)(BAT * HID);  // parity 1
#pragma unroll
    for (int r = 0; r < 16; ++r) {
      int row = i * 32 + r4 + (r & 3) + ((r >> 2) << 3);
      unsigned short h = f2bf(x[r]);
      unsigned short lo = f2bf(x[r] - bf2f(h));
      __hip_atomic_store(dstp + (size_t)row * HID + col,
                         (uint32_t)h | ((uint32_t)lo << 16),
                         __ATOMIC_RELAXED, __HIP_MEMORY_SCOPE_SYSTEM);
    }
  }
  asm volatile("" ::: "memory");
  __builtin_amdgcn_s_waitcnt(0x0f70);  // vmcnt(0): h stores acked at coherence point
  asm volatile("" ::: "memory");
  if (l == 0)
    __hip_atomic_store(&flags[myflag], 1, __ATOMIC_RELAXED, __HIP_MEMORY_SCOPE_SYSTEM);

  // ---- steps 2..255 ----
  for (int s = 2; s <= 255; ++s) {
    float rv[16];
    {  // prefetch R_s (plain loads, clean read-only data) — in flight during spins
      const float4* rp = (const float4*)(Rf + (size_t)s * 131072 + fragbase);
#pragma unroll
      for (int q = 0; q < 4; ++q) {
        float4 a = rp[q];
        rv[q * 4 + 0] = a.x; rv[q * 4 + 1] = a.y;
        rv[q * 4 + 2] = a.z; rv[q * 4 + 3] = a.w;
      }
    }
    const uint32_t* hb = hpk + (size_t)((s - 1) & 1) * (BAT * HID);
    unsigned long long Abuf[32], Bbuf[32];
    floatx16 acc0 = {}, acc1 = {}, acc2 = {};
    WAITG(0); LOADG(0, Abuf);
    WAITG(1); LOADG(1, Bbuf);
    CONSUME(0, Abuf);
    WAITG(2); LOADG(2, Abuf);
    CONSUME(1, Bbuf);
    WAITG(3); LOADG(3, Bbuf);
    CONSUME(2, Abuf);
    CONSUME(3, Bbuf);
#pragma unroll
    for (int r = 0; r < 16; ++r)
      x[r] = fast_tanh(acc0[r] + acc1[r] + acc2[r] + rv[r]);
    if (s < 255) {
      uint32_t* dstp = hpk + (size_t)(s & 1) * (BAT * HID);
#pragma unroll
      for (int r = 0; r < 16; ++r) {
        int row = i * 32 + r4 + (r & 3) + ((r >> 2) << 3);
        unsigned short h = f2bf(x[r]);
        unsigned short lo = f2bf(x[r] - bf2f(h));
        __hip_atomic_store(dstp + (size_t)row * HID + col,
                           (uint32_t)h | ((uint32_t)lo << 16),
                           __ATOMIC_RELAXED, __HIP_MEMORY_SCOPE_SYSTEM);
      }
      asm volatile("" ::: "memory");
      __builtin_amdgcn_s_waitcnt(0x0f70);
      asm volatile("" ::: "memory");
      if (l == 0)
        __hip_atomic_store(&flags[myflag], s, __ATOMIC_RELAXED, __HIP_MEMORY_SCOPE_SYSTEM);
    } else {
#pragma unroll
      for (int r = 0; r < 16; ++r) {
        int row = i * 32 + r4 + (r & 3) + ((r >> 2) << 3);
        out[(size_t)row * HID + col] = x[r];
      }
    }
  }
}

extern "C" void kernel_launch(void* const* d_in, const int* in_sizes, int n_in,
                              void* d_out, int out_size, void* d_ws, size_t ws_size,
                              hipStream_t stream) {
  const int*   tokens = (const int*)d_in[0];
  const float* emb    = (const float*)d_in[1];
  const float* Wl     = (const float*)d_in[2];
  const float* Wr     = (const float*)d_in[3];
  const float* bias   = (const float*)d_in[4];
  float* out = (float*)d_out;
  char* ws = (char*)d_ws;
  const size_t HALF_MB = 1u << 19;
  unsigned short* wlhi = (unsigned short*)(ws + 0 * HALF_MB);
  unsigned short* wllo = (unsigned short*)(ws + 1 * HALF_MB);
  unsigned short* wrhi = (unsigned short*)(ws + 2 * HALF_MB);
  uint32_t*       hpk  = (uint32_t*)(ws + 3 * HALF_MB);  // 2 x 256x512 x u32 = 1MB
  int* flags           = (int*)(ws + 5 * HALF_MB);       // 16KB
  float* Rf            = (float*)(ws + 6 * HALF_MB);     // 134MB f32

  hipLaunchKernelGGL(rk0_frag, dim3(512), dim3(64), 0, stream,
                     Wl, Wr, wlhi, wllo, wrhi, flags);
  hipLaunchKernelGGL(rk1_pre, dim3(8, 64), dim3(256), 0, stream,
                     tokens, emb, bias, wlhi, wrhi, Rf);
  hipLaunchKernelGGL(rk2_rec, dim3(128), dim3(64), 0, stream,
                     wlhi, wllo, Rf, hpk, flags, out);
}